// Round 1
// baseline (168.412 us; speedup 1.0000x reference)
//
#include <hip/hip_runtime.h>

#define NPOS 1024
#define OUTLEN 2048
#define PAD_SYM 4

__global__ __launch_bounds__(256) void ids_gallager_kernel(
    const int* __restrict__ x, const int* __restrict__ mask,
    const int* __restrict__ ins_rand, const int* __restrict__ sub_off,
    int* __restrict__ out, int B)
{
    const int wave = (int)((blockIdx.x * blockDim.x + threadIdx.x) >> 6);
    const int lane = (int)(threadIdx.x & 63);
    if (wave >= B) return;

    const int* xr  = x        + (size_t)wave * NPOS;
    const int* mr  = mask     + (size_t)wave * NPOS;
    const int* irr = ins_rand + (size_t)wave * OUTLEN;
    const int* sor = sub_off  + (size_t)wave * OUTLEN;
    int*       outr = out     + (size_t)wave * OUTLEN;

    // ---- pass 1: load 16 mask values, compute per-lane emit count ----
    int m[16];
    const int4* mv = (const int4*)(mr + lane * 16);
#pragma unroll
    for (int j = 0; j < 4; ++j) {
        int4 t = mv[j];
        m[4*j+0] = t.x; m[4*j+1] = t.y; m[4*j+2] = t.z; m[4*j+3] = t.w;
    }

    int cnt = 0;
#pragma unroll
    for (int k = 0; k < 16; ++k) {
        // contribution: mask 0 -> 2, mask 1 -> 0, mask 2/3 -> 1
        cnt += (m[k] == 0) ? 2 : ((m[k] == 1) ? 0 : 1);
    }

    // ---- wave-wide inclusive scan (64 lanes, 6 steps) ----
    int incl = cnt;
#pragma unroll
    for (int d = 1; d < 64; d <<= 1) {
        int t = __shfl_up(incl, d, 64);
        if (lane >= d) incl += t;
    }
    const int excl  = incl - cnt;
    const int total = __shfl(incl, 63, 64);

    // ---- pass 2: load data, emit at running pointer ----
    const int4* xv = (const int4*)(xr  + lane * 16);
    const int4* iv = (const int4*)(irr + lane * 32);
    const int4* sv = (const int4*)(sor + lane * 32);

    int* p = outr + excl;
#pragma unroll
    for (int j = 0; j < 4; ++j) {
        int4 xt = xv[j];
        int xx[4] = { xt.x, xt.y, xt.z, xt.w };
        int4 i0 = iv[2*j], i1 = iv[2*j+1];
        int ii[8] = { i0.x, i0.y, i0.z, i0.w, i1.x, i1.y, i1.z, i1.w };
        int4 s0 = sv[2*j], s1 = sv[2*j+1];
        int ss[8] = { s0.x, s0.y, s0.z, s0.w, s1.x, s1.y, s1.z, s1.w };
#pragma unroll
        for (int k = 0; k < 4; ++k) {
            int mm = m[4*j+k];
            if (mm == 0) {            // insertion: keep both random symbols
                p[0] = ii[2*k];
                p[1] = ii[2*k+1];
                p += 2;
            } else if (mm == 2) {     // substitution: one symbol, offset mod 4
                p[0] = (xx[k] + ss[2*k] + 1) & 3;
                p += 1;
            } else if (mm == 3) {     // clean: keep one copy
                p[0] = xx[k];
                p += 1;
            }                          // mm == 1: deletion, emit nothing
        }
    }

    // ---- pad tail [total, OUTLEN) with PAD_SYM, wave-cooperative ----
    for (int j = total + lane; j < OUTLEN; j += 64) outr[j] = PAD_SYM;
}

extern "C" void kernel_launch(void* const* d_in, const int* in_sizes, int n_in,
                              void* d_out, int out_size, void* d_ws, size_t ws_size,
                              hipStream_t stream) {
    const int* x        = (const int*)d_in[0];
    const int* mask     = (const int*)d_in[1];
    const int* ins_rand = (const int*)d_in[2];
    const int* sub_off  = (const int*)d_in[3];
    int* out            = (int*)d_out;

    const int B = in_sizes[1] / NPOS;           // mask is [B, N]
    const int waves_per_block = 4;              // 256 threads
    const int blocks = (B + waves_per_block - 1) / waves_per_block;
    ids_gallager_kernel<<<blocks, 256, 0, stream>>>(x, mask, ins_rand, sub_off, out, B);
}

// Round 3
// 109.555 us; speedup vs baseline: 1.5372x; 1.5372x over previous
//
#include <hip/hip_runtime.h>

#define NPOS 1024
#define OUTLEN 2048
#define PAD_SYM 4
#define WAVES_PER_BLOCK 4

typedef int iv4 __attribute__((ext_vector_type(4)));

__global__ __launch_bounds__(256) void ids_gallager_kernel(
    const int* __restrict__ x, const int* __restrict__ mask,
    const int* __restrict__ ins_rand, const int* __restrict__ sub_off,
    int* __restrict__ out, int B)
{
    __shared__ int lds[WAVES_PER_BLOCK][OUTLEN];

    const int wave = (int)((blockIdx.x * blockDim.x + threadIdx.x) >> 6);
    const int w    = (int)(threadIdx.x >> 6);      // wave within block
    const int lane = (int)(threadIdx.x & 63);
    if (wave >= B) return;

    const int* xr  = x        + (size_t)wave * NPOS;
    const int* mr  = mask     + (size_t)wave * NPOS;
    const int* irr = ins_rand + (size_t)wave * OUTLEN;
    const int* sor = sub_off  + (size_t)wave * OUTLEN;
    int*       outr = out     + (size_t)wave * OUTLEN;
    int*       row  = lds[w];

    // ---- pass 1: load 16 mask values, per-lane emit count ----
    int m[16];
    const int4* mv = (const int4*)(mr + lane * 16);
#pragma unroll
    for (int j = 0; j < 4; ++j) {
        int4 t = mv[j];
        m[4*j+0] = t.x; m[4*j+1] = t.y; m[4*j+2] = t.z; m[4*j+3] = t.w;
    }

    int cnt = 0;
#pragma unroll
    for (int k = 0; k < 16; ++k)
        cnt += (m[k] == 0) ? 2 : ((m[k] == 1) ? 0 : 1);

    // ---- wave-wide inclusive scan (64 lanes, 6 steps) ----
    int incl = cnt;
#pragma unroll
    for (int d = 1; d < 64; d <<= 1) {
        int t = __shfl_up(incl, d, 64);
        if (lane >= d) incl += t;
    }
    const int excl  = incl - cnt;
    const int total = __shfl(incl, 63, 64);

    // ---- pass 2: emit into LDS at running pointer (divergence is cheap here) ----
    const int4* xv = (const int4*)(xr  + lane * 16);
    const int4* iv = (const int4*)(irr + lane * 32);
    const int4* sv = (const int4*)(sor + lane * 32);

    int p = excl;
#pragma unroll
    for (int j = 0; j < 4; ++j) {
        int4 xt = xv[j];
        int xx[4] = { xt.x, xt.y, xt.z, xt.w };
        int4 i0 = iv[2*j], i1 = iv[2*j+1];
        int ii[8] = { i0.x, i0.y, i0.z, i0.w, i1.x, i1.y, i1.z, i1.w };
        int4 s0 = sv[2*j], s1 = sv[2*j+1];
        int ss[8] = { s0.x, s0.y, s0.z, s0.w, s1.x, s1.y, s1.z, s1.w };
#pragma unroll
        for (int k = 0; k < 4; ++k) {
            int mm = m[4*j+k];
            if (mm == 0) {            // insertion: keep both random symbols
                row[p]   = ii[2*k];
                row[p+1] = ii[2*k+1];
                p += 2;
            } else if (mm == 2) {     // substitution
                row[p] = (xx[k] + ss[2*k] + 1) & 3;
                p += 1;
            } else if (mm == 3) {     // clean
                row[p] = xx[k];
                p += 1;
            }                          // mm == 1: deletion
        }
    }

    // ---- pad tail [total, OUTLEN) in LDS ----
    for (int j = total + lane; j < OUTLEN; j += 64) row[j] = PAD_SYM;

    __syncthreads();   // order LDS writes before reads

    // ---- coalesced streaming store: 2048 ints = 8 × (64 lanes × int4) ----
#pragma unroll
    for (int k = 0; k < 8; ++k) {
        const iv4 v = *(const iv4*)(row + k * 256 + lane * 4);
        __builtin_nontemporal_store(v, (iv4*)(outr + k * 256 + lane * 4));
    }
}

extern "C" void kernel_launch(void* const* d_in, const int* in_sizes, int n_in,
                              void* d_out, int out_size, void* d_ws, size_t ws_size,
                              hipStream_t stream) {
    const int* x        = (const int*)d_in[0];
    const int* mask     = (const int*)d_in[1];
    const int* ins_rand = (const int*)d_in[2];
    const int* sub_off  = (const int*)d_in[3];
    int* out            = (int*)d_out;

    const int B = in_sizes[1] / NPOS;           // mask is [B, N]
    const int blocks = (B + WAVES_PER_BLOCK - 1) / WAVES_PER_BLOCK;
    ids_gallager_kernel<<<blocks, 256, 0, stream>>>(x, mask, ins_rand, sub_off, out, B);
}

// Round 4
// 72.596 us; speedup vs baseline: 2.3199x; 1.5091x over previous
//
#include <hip/hip_runtime.h>

#define NPOS 1024
#define OUTLEN 2048
#define PAD_SYM 4
#define WAVES_PER_BLOCK 4
#define ROWB 2176   // bytes per wave: 2048 row + 64 dump slots + pad (16B-aligned)

typedef int iv4 __attribute__((ext_vector_type(4)));

__global__ __launch_bounds__(256) void ids_gallager_kernel(
    const int* __restrict__ x, const int* __restrict__ mask,
    const int* __restrict__ ins_rand, const int* __restrict__ sub_off,
    int* __restrict__ out, int B)
{
    __shared__ alignas(16) unsigned char lds[WAVES_PER_BLOCK][ROWB];

    const int wave = (int)((blockIdx.x * blockDim.x + threadIdx.x) >> 6);
    const int w    = (int)(threadIdx.x >> 6);
    const int lane = (int)(threadIdx.x & 63);
    if (wave >= B) return;

    const int* xr  = x        + (size_t)wave * NPOS;
    const int* mr  = mask     + (size_t)wave * NPOS;
    const int* irr = ins_rand + (size_t)wave * OUTLEN;
    const int* sor = sub_off  + (size_t)wave * OUTLEN;
    int*       outr = out     + (size_t)wave * OUTLEN;
    unsigned char* row8  = lds[w];
    int*           row32 = (int*)row8;

    // ---- pass 1: load 16 mask values (same pattern as R3 for FETCH A/B) ----
    int m[16];
    const int4* mv = (const int4*)(mr + lane * 16);
#pragma unroll
    for (int j = 0; j < 4; ++j) {
        int4 t = mv[j];
        m[4*j+0] = t.x; m[4*j+1] = t.y; m[4*j+2] = t.z; m[4*j+3] = t.w;
    }

    int cnt = 0;
#pragma unroll
    for (int k = 0; k < 16; ++k)
        cnt += (m[k] == 0) ? 2 : ((m[k] == 1) ? 0 : 1);

    // ---- wave-wide inclusive scan ----
    int incl = cnt;
#pragma unroll
    for (int d = 1; d < 64; d <<= 1) {
        int t = __shfl_up(incl, d, 64);
        if (lane >= d) incl += t;
    }
    const int excl  = incl - cnt;
    const int total = __shfl(incl, 63, 64);

    // ---- pass 2: branch-free emit into byte row; dead writes -> dump slot ----
    const int4* xv = (const int4*)(xr  + lane * 16);
    const int4* iv = (const int4*)(irr + lane * 32);
    const int4* sv = (const int4*)(sor + lane * 32);

    int p = excl;
    const int dump = OUTLEN + lane;          // per-lane garbage slot
#pragma unroll
    for (int j = 0; j < 4; ++j) {
        int4 xt = xv[j];
        int xx[4] = { xt.x, xt.y, xt.z, xt.w };
        int4 i0 = iv[2*j], i1 = iv[2*j+1];
        int ii[8] = { i0.x, i0.y, i0.z, i0.w, i1.x, i1.y, i1.z, i1.w };
        int4 s0 = sv[2*j], s1 = sv[2*j+1];
        int ss[8] = { s0.x, s0.y, s0.z, s0.w, s1.x, s1.y, s1.z, s1.w };
#pragma unroll
        for (int k = 0; k < 4; ++k) {
            const int mm = m[4*j+k];
            const int c  = (mm == 0) ? 2 : ((mm == 1) ? 0 : 1);
            const int sub = (xx[k] + ss[2*k] + 1) & 3;
            const int e0  = (mm == 0) ? ii[2*k] : ((mm == 2) ? sub : xx[k]);
            row8[(c != 0) ? p       : dump] = (unsigned char)e0;
            row8[(c == 2) ? (p + 1) : dump] = (unsigned char)ii[2*k+1];
            p += c;
        }
    }

    // ---- pad tail bytes [total, OUTLEN) with PAD_SYM ----
    const int a4 = (total + 3) & ~3;               // first 4-aligned byte
    if (lane < a4 - total) row8[total + lane] = (unsigned char)PAD_SYM;
    for (int j4 = (a4 >> 2) + lane; j4 < (OUTLEN >> 2); j4 += 64)
        row32[j4] = 0x04040404;

    __syncthreads();   // LDS visibility across lanes before readback

    // ---- store: lane reads 1 dword (4 symbols), widens, NT int4 store ----
#pragma unroll
    for (int k = 0; k < 8; ++k) {
        const unsigned int d = *(const unsigned int*)(row8 + k * 256 + lane * 4);
        iv4 v;
        v.x = (int)(d & 0xffu);
        v.y = (int)((d >> 8)  & 0xffu);
        v.z = (int)((d >> 16) & 0xffu);
        v.w = (int)(d >> 24);
        __builtin_nontemporal_store(v, (iv4*)(outr + k * 256 + lane * 4));
    }
}

extern "C" void kernel_launch(void* const* d_in, const int* in_sizes, int n_in,
                              void* d_out, int out_size, void* d_ws, size_t ws_size,
                              hipStream_t stream) {
    const int* x        = (const int*)d_in[0];
    const int* mask     = (const int*)d_in[1];
    const int* ins_rand = (const int*)d_in[2];
    const int* sub_off  = (const int*)d_in[3];
    int* out            = (int*)d_out;

    const int B = in_sizes[1] / NPOS;           // mask is [B, N]
    const int blocks = (B + WAVES_PER_BLOCK - 1) / WAVES_PER_BLOCK;
    ids_gallager_kernel<<<blocks, 256, 0, stream>>>(x, mask, ins_rand, sub_off, out, B);
}

// Round 5
// 44.175 us; speedup vs baseline: 3.8123x; 1.6434x over previous
//
#include <hip/hip_runtime.h>

#define NPOS 1024
#define OUTLEN 2048
#define PAD_SYM 4
#define WAVES_PER_BLOCK 4
#define WBUF 5120   // per-wave LDS bytes: mask 1K | x 1K | ins 2K | subE 1K

typedef int iv4 __attribute__((ext_vector_type(4)));

#define BYTE_OF(dw, b) ((int)(((unsigned)(dw) >> ((b) * 8)) & 0xffu))

__device__ __forceinline__ unsigned pack4(int4 t) {
    // all values < 256
    return (unsigned)t.x | ((unsigned)t.y << 8) | ((unsigned)t.z << 16) | ((unsigned)t.w << 24);
}

__global__ __launch_bounds__(256) void ids_gallager_kernel(
    const int* __restrict__ x, const int* __restrict__ mask,
    const int* __restrict__ ins_rand, const int* __restrict__ sub_off,
    int* __restrict__ out, int B)
{
    __shared__ alignas(16) unsigned char lds[WAVES_PER_BLOCK][WBUF];

    const int wave = (int)(blockIdx.x * WAVES_PER_BLOCK + (threadIdx.x >> 6));
    const int w    = (int)(threadIdx.x >> 6);
    const int lane = (int)(threadIdx.x & 63);
    if (wave >= B) return;

    unsigned char* buf  = lds[w];
    int*           buf32 = (int*)buf;
    int* outr = out + (size_t)wave * OUTLEN;

    // ---- stage: fully lane-contiguous global loads, byte-pack, LDS write ----
    const int4* mv = (const int4*)(mask     + (size_t)wave * NPOS);    // 256 int4
    const int4* xv = (const int4*)(x        + (size_t)wave * NPOS);
    const int4* ivv = (const int4*)(ins_rand + (size_t)wave * OUTLEN); // 512 int4
    const int4* svv = (const int4*)(sub_off  + (size_t)wave * OUTLEN);

#pragma unroll
    for (int j = 0; j < 4; ++j) {
        *(unsigned*)(buf +         j * 256 + lane * 4) = pack4(mv[j * 64 + lane]);
        *(unsigned*)(buf + 1024 +  j * 256 + lane * 4) = pack4(xv[j * 64 + lane]);
    }
#pragma unroll
    for (int j = 0; j < 8; ++j)
        *(unsigned*)(buf + 2048 + j * 256 + lane * 4) = pack4(ivv[j * 64 + lane]);
#pragma unroll
    for (int j = 0; j < 8; ++j) {
        int4 t = svv[j * 64 + lane];  // only even slots (.x, .z) are ever used
        *(unsigned short*)(buf + 4096 + j * 128 + lane * 2) =
            (unsigned short)((unsigned)t.x | ((unsigned)t.z << 8));
    }

    __syncthreads();

    // ---- pull this lane's 16 consecutive positions back into registers ----
    const iv4 mdw  = *(const iv4*)(buf +        lane * 16);  // 16 mask bytes
    const iv4 xdw  = *(const iv4*)(buf + 1024 + lane * 16);  // 16 x bytes
    const iv4 idw0 = *(const iv4*)(buf + 2048 + lane * 32);  // ins bytes 0..15
    const iv4 idw1 = *(const iv4*)(buf + 2048 + lane * 32 + 16); // ins bytes 16..31
    const iv4 sdw  = *(const iv4*)(buf + 4096 + lane * 16);  // 16 even sub bytes

    // ---- per-lane emit count ----
    int mb[16];
    int cnt = 0;
#pragma unroll
    for (int j = 0; j < 4; ++j) {
#pragma unroll
        for (int k = 0; k < 4; ++k) {
            const int mm = BYTE_OF(mdw[j], k);
            mb[4 * j + k] = mm;
            cnt += (mm == 0) ? 2 : ((mm == 1) ? 0 : 1);
        }
    }

    // ---- wave-wide inclusive scan ----
    int incl = cnt;
#pragma unroll
    for (int d = 1; d < 64; d <<= 1) {
        int t = __shfl_up(incl, d, 64);
        if (lane >= d) incl += t;
    }
    const int excl  = incl - cnt;
    const int total = __shfl(incl, 63, 64);

    // ---- branch-free emit into byte row buf[0..2048); dump slots at 2048+lane ----
    // (clobbers staged mask/x/ins[0..64) regions — already in registers)
    int p = excl;
    const int dump = OUTLEN + lane;
#pragma unroll
    for (int j = 0; j < 4; ++j) {
#pragma unroll
        for (int k = 0; k < 4; ++k) {
            const int mm = mb[4 * j + k];
            const int c  = (mm == 0) ? 2 : ((mm == 1) ? 0 : 1);
            const int xx = BYTE_OF(xdw[j], k);
            const int q  = 2 * j + (k >> 1);               // compile-time const
            const unsigned insq = (unsigned)((q < 4) ? idw0[q] : idw1[q - 4]);
            const int iA = BYTE_OF(insq, (2 * k) & 3);
            const int iB = BYTE_OF(insq, ((2 * k) & 3) + 1);
            const int sO = BYTE_OF(sdw[j], k);
            const int sub = (xx + sO + 1) & 3;
            const int e0  = (mm == 0) ? iA : ((mm == 2) ? sub : xx);
            buf[(c != 0) ? p       : dump] = (unsigned char)e0;
            buf[(c == 2) ? (p + 1) : dump] = (unsigned char)iB;
            p += c;
        }
    }

    // ---- pad tail bytes [total, OUTLEN) with PAD_SYM ----
    const int a4 = (total + 3) & ~3;
    if (lane < a4 - total) buf[total + lane] = (unsigned char)PAD_SYM;
    for (int j4 = (a4 >> 2) + lane; j4 < (OUTLEN >> 2); j4 += 64)
        buf32[j4] = 0x04040404;

    __syncthreads();

    // ---- store: lane reads 1 dword (4 symbols), widens, NT int4 store ----
#pragma unroll
    for (int k = 0; k < 8; ++k) {
        const unsigned int d = *(const unsigned int*)(buf + k * 256 + lane * 4);
        iv4 v;
        v.x = (int)(d & 0xffu);
        v.y = (int)((d >> 8)  & 0xffu);
        v.z = (int)((d >> 16) & 0xffu);
        v.w = (int)(d >> 24);
        __builtin_nontemporal_store(v, (iv4*)(outr + k * 256 + lane * 4));
    }
}

extern "C" void kernel_launch(void* const* d_in, const int* in_sizes, int n_in,
                              void* d_out, int out_size, void* d_ws, size_t ws_size,
                              hipStream_t stream) {
    const int* x        = (const int*)d_in[0];
    const int* mask     = (const int*)d_in[1];
    const int* ins_rand = (const int*)d_in[2];
    const int* sub_off  = (const int*)d_in[3];
    int* out            = (int*)d_out;

    const int B = in_sizes[1] / NPOS;           // mask is [B, N]
    const int blocks = (B + WAVES_PER_BLOCK - 1) / WAVES_PER_BLOCK;
    ids_gallager_kernel<<<blocks, 256, 0, stream>>>(x, mask, ins_rand, sub_off, out, B);
}

// Round 6
// 42.645 us; speedup vs baseline: 3.9492x; 1.0359x over previous
//
#include <hip/hip_runtime.h>

#define NPOS 1024
#define OUTLEN 2048
#define PAD_SYM 4
#define WAVES_PER_BLOCK 4
#define ROWB 2176   // 2048 row bytes + 64 dump slots + pad

typedef int iv4 __attribute__((ext_vector_type(4)));

__global__ __launch_bounds__(256) void ids_gallager_kernel(
    const int* __restrict__ x, const int* __restrict__ mask,
    const int* __restrict__ ins_rand, const int* __restrict__ sub_off,
    int* __restrict__ out, int B)
{
    __shared__ alignas(16) unsigned char lds[WAVES_PER_BLOCK][ROWB];

    const int wave = (int)(blockIdx.x * WAVES_PER_BLOCK + (threadIdx.x >> 6));
    const int w    = (int)(threadIdx.x >> 6);
    const int lane = (int)(threadIdx.x & 63);
    if (wave >= B) return;

    const int4* mv  = (const int4*)(mask     + (size_t)wave * NPOS);   // 256 int4
    const int4* xv  = (const int4*)(x        + (size_t)wave * NPOS);
    const int4* ivv = (const int4*)(ins_rand + (size_t)wave * OUTLEN); // 512 int4
    const int4* svv = (const int4*)(sub_off  + (size_t)wave * OUTLEN);
    int* outr = out + (size_t)wave * OUTLEN;

    unsigned char* row   = lds[w];
    int*           row32 = (int*)row;
    const int dump = OUTLEN + lane;

    // ---- 4 chunks of 256 positions; lane owns positions 4l..4l+3 ----
    int carry = 0;
#pragma unroll
    for (int c = 0; c < 4; ++c) {
        // direct, coalesced loads (no LDS staging)
        const int4 mt = mv[c * 64 + lane];            // stride 16B
        const int4 xt = xv[c * 64 + lane];
        const int4 i0 = ivv[c * 128 + 2 * lane];      // stride 32B
        const int4 i1 = ivv[c * 128 + 2 * lane + 1];
        const int4 s0 = svv[c * 128 + 2 * lane];
        const int4 s1 = svv[c * 128 + 2 * lane + 1];

        const int mm[4] = { mt.x, mt.y, mt.z, mt.w };
        const int xx[4] = { xt.x, xt.y, xt.z, xt.w };
        const int iA[4] = { i0.x, i0.z, i1.x, i1.z }; // even doubled slots
        const int iB[4] = { i0.y, i0.w, i1.y, i1.w }; // odd doubled slots
        const int sO[4] = { s0.x, s0.z, s1.x, s1.z }; // sub_off at even slots

        int cnt = 0;
#pragma unroll
        for (int k = 0; k < 4; ++k)
            cnt += (mm[k] == 0) ? 2 : ((mm[k] == 1) ? 0 : 1);

        // wave-wide inclusive scan for this chunk
        int incl = cnt;
#pragma unroll
        for (int d = 1; d < 64; d <<= 1) {
            int t = __shfl_up(incl, d, 64);
            if (lane >= d) incl += t;
        }
        int p = carry + incl - cnt;                   // global exclusive offset
        carry += __shfl(incl, 63, 64);                // chunk total

        // branch-free emit; dead writes go to per-lane dump slot
#pragma unroll
        for (int k = 0; k < 4; ++k) {
            const int m_  = mm[k];
            const int cc  = (m_ == 0) ? 2 : ((m_ == 1) ? 0 : 1);
            const int sub = (xx[k] + sO[k] + 1) & 3;
            const int e0  = (m_ == 0) ? iA[k] : ((m_ == 2) ? sub : xx[k]);
            row[(cc != 0) ? p       : dump] = (unsigned char)e0;
            row[(cc == 2) ? (p + 1) : dump] = (unsigned char)iB[k];
            p += cc;
        }
    }
    const int total = carry;

    // ---- pad tail bytes [total, OUTLEN) with PAD_SYM ----
    const int a4 = (total + 3) & ~3;
    if (lane < a4 - total) row[total + lane] = (unsigned char)PAD_SYM;
    for (int j4 = (a4 >> 2) + lane; j4 < (OUTLEN >> 2); j4 += 64)
        row32[j4] = 0x04040404;

    __syncthreads();   // cheap; orders LDS before readback

    // ---- store: lane reads 1 dword (4 symbols), widens, NT int4 store ----
#pragma unroll
    for (int k = 0; k < 8; ++k) {
        const unsigned int d = *(const unsigned int*)(row + k * 256 + lane * 4);
        iv4 v;
        v.x = (int)(d & 0xffu);
        v.y = (int)((d >> 8)  & 0xffu);
        v.z = (int)((d >> 16) & 0xffu);
        v.w = (int)(d >> 24);
        __builtin_nontemporal_store(v, (iv4*)(outr + k * 256 + lane * 4));
    }
}

extern "C" void kernel_launch(void* const* d_in, const int* in_sizes, int n_in,
                              void* d_out, int out_size, void* d_ws, size_t ws_size,
                              hipStream_t stream) {
    const int* x        = (const int*)d_in[0];
    const int* mask     = (const int*)d_in[1];
    const int* ins_rand = (const int*)d_in[2];
    const int* sub_off  = (const int*)d_in[3];
    int* out            = (int*)d_out;

    const int B = in_sizes[1] / NPOS;           // mask is [B, N]
    const int blocks = (B + WAVES_PER_BLOCK - 1) / WAVES_PER_BLOCK;
    ids_gallager_kernel<<<blocks, 256, 0, stream>>>(x, mask, ins_rand, sub_off, out, B);
}